// Round 6
// baseline (271.733 us; speedup 1.0000x reference)
//
#include <hip/hip_runtime.h>
#include <stdint.h>

#define Hh 512
#define Ww 768
#define HW (Hh*Ww)
#define Bb 4
#define Cc 129
#define DESC 128
#define KK 2048
#define CAND_CAP 32768
#define SORT_CAP 4096
#define NBINS 4096
#define CHUNKS 13                      // ceil(768/60): 60 outputs per wave + 2+2 halo lanes
#define WAVES_TOTAL (Bb*Hh*CHUNKS)     // 26624
#define NMS_BLOCKS (WAVES_TOTAL/4)     // 6656

__global__ void zero_counters(uint32_t* cnt) {
    if (threadIdx.x < Bb) cnt[threadIdx.x] = 0u;
}

// Separable 5x5 NMS: 5 independent column loads + vertical fmax + horizontal max via shuffles.
__global__ __launch_bounds__(256) void nms_collect(const float* __restrict__ unet,
                                                   uint64_t* __restrict__ cand,
                                                   uint32_t* __restrict__ cnt) {
    __shared__ uint32_t wcnt[4];
    __shared__ uint32_t sbase;
    int wid = threadIdx.x >> 6;
    int lane = threadIdx.x & 63;
    int w = blockIdx.x * 4 + wid;
    int chunk = w % CHUNKS;
    int t = w / CHUNKS;
    int y = t & (Hh - 1);
    int b = t >> 9;
    int x = chunk * 60 + lane - 2;
    int xc = min(max(x, 0), Ww - 1);
    const float* hb = unet + ((size_t)(b * Cc + DESC)) * HW;

    int y0 = max(y - 2, 0), y1 = max(y - 1, 0);
    int y3 = min(y + 1, Hh - 1), y4 = min(y + 2, Hh - 1);
    float r0 = hb[y0 * Ww + xc];            // 5 independent loads, one wait
    float r1 = hb[y1 * Ww + xc];
    float r2 = hb[y  * Ww + xc];
    float r3 = hb[y3 * Ww + xc];
    float r4 = hb[y4 * Ww + xc];
    float cm = fmaxf(fmaxf(fmaxf(r0, r1), fmaxf(r3, r4)), r2);
    float m1 = fmaxf(__shfl(cm, lane - 1), __shfl(cm, lane + 1));
    float m2 = fmaxf(__shfl(cm, lane - 2), __shfl(cm, lane + 2));
    float hm = fmaxf(cm, fmaxf(m1, m2));    // max over clamped 5x5 == -inf-pad max for survival
    bool valid = (lane >= 2) && (lane <= 61) && (x < Ww);
    bool surv = valid && (r2 > 0.0f) && (r2 >= hm);

    uint64_t ball = __ballot(surv);
    uint32_t my = __popcll(ball & ((1ull << lane) - 1ull));
    if (lane == 0) wcnt[wid] = (uint32_t)__popcll(ball);
    __syncthreads();
    uint32_t wbase = 0;
    #pragma unroll
    for (int i = 0; i < 4; ++i) wbase += (i < wid) ? wcnt[i] : 0u;
    if (threadIdx.x == 0) {
        uint32_t tot = wcnt[0] + wcnt[1] + wcnt[2] + wcnt[3];
        sbase = tot ? atomicAdd(&cnt[b], tot) : 0u;
    }
    __syncthreads();
    if (surv) {
        uint32_t pos_out = sbase + wbase + my;
        if (pos_out < CAND_CAP) {
            uint32_t r = (uint32_t)(y * Ww + x);
            cand[(size_t)b * CAND_CAP + pos_out] =
                ((uint64_t)__float_as_uint(r2) << 32) | (uint32_t)(~r);
        }
    }
}

// Per-batch rank-by-counting top-k (no sort), then counting-sort winners by row y
// so the gather walks memory in spatial order.
__global__ __launch_bounds__(1024) void topk_rank(const uint64_t* __restrict__ cand,
                                                  const uint32_t* __restrict__ cnt,
                                                  float* __restrict__ out,
                                                  uint64_t* __restrict__ kp_sorted) {
    __shared__ uint32_t S[NBINS + 8];
    __shared__ uint32_t scan[1024];
    __shared__ uint64_t keys2[SORT_CAP];
    __shared__ uint32_t rnk[SORT_CAP];
    __shared__ uint32_t ybins[Hh];
    __shared__ uint32_t sThr;
    int b = blockIdx.x;
    int tid = threadIdx.x;
    uint32_t n = cnt[b];
    if (n > CAND_CAP) n = CAND_CAP;
    const uint64_t* cb = cand + (size_t)b * CAND_CAP;

    for (int i = tid; i < NBINS + 8; i += 1024) S[i] = 0u;
    for (int i = tid; i < Hh; i += 1024) ybins[i] = 0u;
    if (tid == 0) sThr = 0u;
    __syncthreads();

    for (uint32_t i = tid; i < n; i += 1024)
        atomicAdd(&S[(uint32_t)(cb[i] >> 51)], 1u);   // bin = value_bits>>19 (<4096, v>0)
    __syncthreads();

    // hist -> per-bin suffix counts (in place); thread t owns bins [4t,4t+4)
    uint32_t h0 = S[4*tid], h1 = S[4*tid+1], h2 = S[4*tid+2], h3 = S[4*tid+3];
    scan[tid] = h0 + h1 + h2 + h3;
    __syncthreads();
    #pragma unroll
    for (int off = 1; off < 1024; off <<= 1) {
        uint32_t v = scan[tid] + ((tid + off < 1024) ? scan[tid + off] : 0u);
        __syncthreads();
        scan[tid] = v;
        __syncthreads();
    }
    {
        uint32_t sfx4 = (tid < 1023) ? scan[tid + 1] : 0u;
        uint32_t S3 = h3 + sfx4, S2 = h2 + S3, S1 = h1 + S2, S0 = h0 + S1;
        S[4*tid] = S0; S[4*tid+1] = S1; S[4*tid+2] = S2; S[4*tid+3] = S3;
        if (S3 >= KK && sfx4 < KK) sThr = (uint32_t)(4*tid + 3);
        if (S2 >= KK && S3   < KK) sThr = (uint32_t)(4*tid + 2);
        if (S1 >= KK && S2   < KK) sThr = (uint32_t)(4*tid + 1);
        if (S0 >= KK && S1   < KK) sThr = (uint32_t)(4*tid + 0);
    }
    __syncthreads();

    uint32_t thr = sThr;
    uint32_t m = S[thr];
    if (m > SORT_CAP) m = SORT_CAP;

    // counting-scatter: bin-grouped; post-scatter S[b+1] = S_old[b]
    for (uint32_t i = tid; i < n; i += 1024) {
        uint64_t key = cb[i];
        uint32_t bin = (uint32_t)(key >> 51);
        if (bin >= thr) {
            uint32_t p = atomicAdd(&S[bin + 1], 1u);
            if (p < SORT_CAP) keys2[p] = key;
        }
    }
    __syncthreads();

    // ranks + coordinate/score emit
    float* out_kp = out;                      // (B,K,2)
    float* out_sc = out + (size_t)Bb * KK * 2;
    for (uint32_t p = tid; p < m; p += 1024) {
        uint64_t key = keys2[p];
        uint32_t bin = (uint32_t)(key >> 51);
        uint32_t base = S[bin + 2];           // = S_old[bin+1]
        uint32_t end  = S[bin + 1];           // = S_old[bin]
        if (end > m) end = m;
        uint32_t rank = base;
        for (uint32_t q = base; q < end; ++q)
            rank += (keys2[q] > key) ? 1u : 0u;
        rnk[p] = rank;
        if (rank < KK) {
            uint32_t idx = ~((uint32_t)key);
            uint32_t yy = idx / Ww, xx = idx - yy * Ww;
            size_t o = (size_t)b * KK + rank;
            out_kp[o * 2 + 0] = (float)xx;
            out_kp[o * 2 + 1] = (float)yy;
            out_sc[o] = __uint_as_float((uint32_t)(key >> 32));
        }
    }
    __syncthreads();

    // y-histogram of winners
    for (uint32_t p = tid; p < m; p += 1024) {
        if (rnk[p] < KK) {
            uint32_t idx = ~((uint32_t)keys2[p]);
            atomicAdd(&ybins[idx / Ww], 1u);
        }
    }
    __syncthreads();

    // exclusive scan of ybins
    uint32_t hv = 0;
    if (tid < Hh) { hv = ybins[tid]; scan[tid] = hv; }
    __syncthreads();
    for (int off = 1; off < Hh; off <<= 1) {
        uint32_t v2 = 0;
        if (tid < Hh) v2 = scan[tid] + ((tid >= off) ? scan[tid - off] : 0u);
        __syncthreads();
        if (tid < Hh) scan[tid] = v2;
        __syncthreads();
    }
    if (tid < Hh) ybins[tid] = scan[tid] - hv;   // exclusive base; reused as cursor
    __syncthreads();

    // scatter winners grouped by y: kp_sorted[b*KK + j] = (rank<<32)|idx
    for (uint32_t p = tid; p < m; p += 1024) {
        uint32_t rank = rnk[p];
        if (rank < KK) {
            uint32_t idx = ~((uint32_t)keys2[p]);
            uint32_t j = atomicAdd(&ybins[idx / Ww], 1u);
            kp_sorted[(size_t)b * KK + j] = ((uint64_t)rank << 32) | idx;
        }
    }
}

// 4 keypoints per 256-thread block (one per wave), in y-sorted order for DRAM locality.
__global__ __launch_bounds__(256) void gather_desc(const float* __restrict__ unet,
                                                   const uint64_t* __restrict__ kp_sorted,
                                                   float* __restrict__ out_desc) {
    int kp = blockIdx.x * 4 + (threadIdx.x >> 6);
    int lane = threadIdx.x & 63;
    int b = kp >> 11;
    uint64_t e = kp_sorted[kp];
    uint32_t idx  = (uint32_t)e;
    uint32_t rank = (uint32_t)(e >> 32);
    float v0 = 0.0f, v1 = 0.0f;
    if (idx < (uint32_t)HW) {
        const float* base = unet + (size_t)b * Cc * HW + idx;
        v0 = base[(size_t)lane * HW];
        v1 = base[(size_t)(lane + 64) * HW];
    }
    float s = v0 * v0 + v1 * v1;
    #pragma unroll
    for (int off = 32; off > 0; off >>= 1) s += __shfl_xor(s, off);
    float rn = 1.0f / fmaxf(sqrtf(s), 1e-12f);
    if (rank < KK) {
        float* o = out_desc + ((size_t)b * KK + rank) * DESC;
        o[lane]      = v0 * rn;
        o[lane + 64] = v1 * rn;
    }
}

extern "C" void kernel_launch(void* const* d_in, const int* in_sizes, int n_in,
                              void* d_out, int out_size, void* d_ws, size_t ws_size,
                              hipStream_t stream) {
    const float* unet = (const float*)d_in[0];
    float* out = (float*)d_out;
    uint8_t* ws = (uint8_t*)d_ws;

    uint64_t* cand      = (uint64_t*)ws;                                    // 1 MiB
    uint32_t* cnt       = (uint32_t*)(ws + (size_t)Bb * CAND_CAP * 8);      // 16 B
    uint64_t* kp_sorted = (uint64_t*)(ws + (size_t)Bb * CAND_CAP * 8 + 64); // 64 KiB

    float* out_desc = out + (size_t)Bb * KK * 2 + (size_t)Bb * KK;

    zero_counters<<<1, 64, 0, stream>>>(cnt);
    nms_collect<<<NMS_BLOCKS, 256, 0, stream>>>(unet, cand, cnt);
    topk_rank<<<Bb, 1024, 0, stream>>>(cand, cnt, out, kp_sorted);
    // INSTRUMENTATION: gather is idempotent; 5 identical launches so the
    // round-over-round dur delta measures 4x(gather + launch overhead).
    gather_desc<<<Bb * KK / 4, 256, 0, stream>>>(unet, kp_sorted, out_desc);
    gather_desc<<<Bb * KK / 4, 256, 0, stream>>>(unet, kp_sorted, out_desc);
    gather_desc<<<Bb * KK / 4, 256, 0, stream>>>(unet, kp_sorted, out_desc);
    gather_desc<<<Bb * KK / 4, 256, 0, stream>>>(unet, kp_sorted, out_desc);
    gather_desc<<<Bb * KK / 4, 256, 0, stream>>>(unet, kp_sorted, out_desc);
}

// Round 7
// 136.052 us; speedup vs baseline: 1.9973x; 1.9973x over previous
//
#include <hip/hip_runtime.h>
#include <stdint.h>

#define Hh 512
#define Ww 768
#define HW (Hh*Ww)
#define Bb 4
#define Cc 129
#define DESC 128
#define KK 2048
#define NSEG 64
#define SEG_CAP 512
#define CAND_CAP (NSEG*SEG_CAP)        // 32768 per batch
#define SORT_CAP 4096
#define NBINS 4096
#define CHUNKS 13                      // ceil(768/60): 60 outputs per wave + 2+2 halo lanes
#define WAVES_TOTAL (Bb*Hh*CHUNKS)     // 26624
#define NMS_BLOCKS (WAVES_TOTAL/4)     // 6656 (batch boundary 6656%4==0: blocks never span batches)

__global__ void zero_counters(uint32_t* cnt) {
    cnt[threadIdx.x] = 0u;             // Bb*NSEG = 256 counters
}

// Separable 5x5 NMS: 5 column loads + vertical fmax + horizontal max via shuffles.
// Candidate emit: 1 atomic per block, spread over 64 counters/batch (each owns a
// fixed 512-entry cand segment) to kill same-address atomic serialization.
__global__ __launch_bounds__(256) void nms_collect(const float* __restrict__ unet,
                                                   uint64_t* __restrict__ cand,
                                                   uint32_t* __restrict__ cnt) {
    __shared__ uint32_t wcnt[4];
    __shared__ uint32_t sbase;
    int wid = threadIdx.x >> 6;
    int lane = threadIdx.x & 63;
    int w = blockIdx.x * 4 + wid;
    int chunk = w % CHUNKS;
    int t = w / CHUNKS;
    int y = t & (Hh - 1);
    int b = t >> 9;
    int x = chunk * 60 + lane - 2;
    int xc = min(max(x, 0), Ww - 1);
    const float* hb = unet + ((size_t)(b * Cc + DESC)) * HW;

    int y0 = max(y - 2, 0), y1 = max(y - 1, 0);
    int y3 = min(y + 1, Hh - 1), y4 = min(y + 2, Hh - 1);
    float r0 = hb[y0 * Ww + xc];
    float r1 = hb[y1 * Ww + xc];
    float r2 = hb[y  * Ww + xc];
    float r3 = hb[y3 * Ww + xc];
    float r4 = hb[y4 * Ww + xc];
    float cm = fmaxf(fmaxf(fmaxf(r0, r1), fmaxf(r3, r4)), r2);
    float m1 = fmaxf(__shfl(cm, lane - 1), __shfl(cm, lane + 1));
    float m2 = fmaxf(__shfl(cm, lane - 2), __shfl(cm, lane + 2));
    float hm = fmaxf(cm, fmaxf(m1, m2));
    bool valid = (lane >= 2) && (lane <= 61) && (x < Ww);
    bool surv = valid && (r2 > 0.0f) && (r2 >= hm);

    uint64_t ball = __ballot(surv);
    uint32_t my = __popcll(ball & ((1ull << lane) - 1ull));
    if (lane == 0) wcnt[wid] = (uint32_t)__popcll(ball);
    __syncthreads();
    uint32_t wbase = 0;
    #pragma unroll
    for (int i = 0; i < 4; ++i) wbase += (i < wid) ? wcnt[i] : 0u;
    int seg = blockIdx.x & (NSEG - 1);
    if (threadIdx.x == 0) {
        uint32_t tot = wcnt[0] + wcnt[1] + wcnt[2] + wcnt[3];
        sbase = tot ? atomicAdd(&cnt[b * NSEG + seg], tot) : 0u;
    }
    __syncthreads();
    if (surv) {
        uint32_t pos_out = sbase + wbase + my;
        if (pos_out < SEG_CAP) {
            uint32_t r = (uint32_t)(y * Ww + x);
            cand[(size_t)b * CAND_CAP + seg * SEG_CAP + pos_out] =
                ((uint64_t)__float_as_uint(r2) << 32) | (uint32_t)(~r);
        }
    }
}

// Per-batch rank-by-counting top-k over segmented candidate lists, then
// counting-sort winners by row y for gather locality.
__global__ __launch_bounds__(1024) void topk_rank(const uint64_t* __restrict__ cand,
                                                  const uint32_t* __restrict__ cnt,
                                                  float* __restrict__ out,
                                                  uint64_t* __restrict__ kp_sorted) {
    __shared__ uint32_t S[NBINS + 8];
    __shared__ uint32_t scan[1024];
    __shared__ uint64_t keys2[SORT_CAP];
    __shared__ uint32_t rnk[SORT_CAP];
    __shared__ uint32_t ybins[Hh];
    __shared__ uint32_t scnt[NSEG];
    __shared__ uint32_t sThr;
    int b = blockIdx.x;
    int tid = threadIdx.x;
    const uint64_t* cb = cand + (size_t)b * CAND_CAP;

    for (int i = tid; i < NBINS + 8; i += 1024) S[i] = 0u;
    for (int i = tid; i < Hh; i += 1024) ybins[i] = 0u;
    if (tid < NSEG) scnt[tid] = min(cnt[b * NSEG + tid], (uint32_t)SEG_CAP);
    if (tid == 0) sThr = 0u;
    __syncthreads();

    for (uint32_t i = tid; i < CAND_CAP; i += 1024) {
        if ((i & (SEG_CAP - 1)) < scnt[i >> 9])
            atomicAdd(&S[(uint32_t)(cb[i] >> 51)], 1u);   // bin = value_bits>>19
    }
    __syncthreads();

    // hist -> per-bin suffix counts (in place); thread t owns bins [4t,4t+4)
    uint32_t h0 = S[4*tid], h1 = S[4*tid+1], h2 = S[4*tid+2], h3 = S[4*tid+3];
    scan[tid] = h0 + h1 + h2 + h3;
    __syncthreads();
    #pragma unroll
    for (int off = 1; off < 1024; off <<= 1) {
        uint32_t v = scan[tid] + ((tid + off < 1024) ? scan[tid + off] : 0u);
        __syncthreads();
        scan[tid] = v;
        __syncthreads();
    }
    {
        uint32_t sfx4 = (tid < 1023) ? scan[tid + 1] : 0u;
        uint32_t S3 = h3 + sfx4, S2 = h2 + S3, S1 = h1 + S2, S0 = h0 + S1;
        S[4*tid] = S0; S[4*tid+1] = S1; S[4*tid+2] = S2; S[4*tid+3] = S3;
        if (S3 >= KK && sfx4 < KK) sThr = (uint32_t)(4*tid + 3);
        if (S2 >= KK && S3   < KK) sThr = (uint32_t)(4*tid + 2);
        if (S1 >= KK && S2   < KK) sThr = (uint32_t)(4*tid + 1);
        if (S0 >= KK && S1   < KK) sThr = (uint32_t)(4*tid + 0);
    }
    __syncthreads();

    uint32_t thr = sThr;
    uint32_t m = S[thr];
    if (m > SORT_CAP) m = SORT_CAP;

    // counting-scatter: bin-grouped; post-scatter S[b+1] = S_old[b]
    for (uint32_t i = tid; i < CAND_CAP; i += 1024) {
        if ((i & (SEG_CAP - 1)) < scnt[i >> 9]) {
            uint64_t key = cb[i];
            uint32_t bin = (uint32_t)(key >> 51);
            if (bin >= thr) {
                uint32_t p = atomicAdd(&S[bin + 1], 1u);
                if (p < SORT_CAP) keys2[p] = key;
            }
        }
    }
    __syncthreads();

    // ranks + coordinate/score emit
    float* out_kp = out;                      // (B,K,2)
    float* out_sc = out + (size_t)Bb * KK * 2;
    for (uint32_t p = tid; p < m; p += 1024) {
        uint64_t key = keys2[p];
        uint32_t bin = (uint32_t)(key >> 51);
        uint32_t base = S[bin + 2];           // = S_old[bin+1]
        uint32_t end  = S[bin + 1];           // = S_old[bin]
        if (end > m) end = m;
        uint32_t rank = base;
        for (uint32_t q = base; q < end; ++q)
            rank += (keys2[q] > key) ? 1u : 0u;
        rnk[p] = rank;
        if (rank < KK) {
            uint32_t idx = ~((uint32_t)key);
            uint32_t yy = idx / Ww, xx = idx - yy * Ww;
            size_t o = (size_t)b * KK + rank;
            out_kp[o * 2 + 0] = (float)xx;
            out_kp[o * 2 + 1] = (float)yy;
            out_sc[o] = __uint_as_float((uint32_t)(key >> 32));
        }
    }
    __syncthreads();

    // y-histogram of winners
    for (uint32_t p = tid; p < m; p += 1024) {
        if (rnk[p] < KK) {
            uint32_t idx = ~((uint32_t)keys2[p]);
            atomicAdd(&ybins[idx / Ww], 1u);
        }
    }
    __syncthreads();

    // exclusive scan of ybins
    uint32_t hv = 0;
    if (tid < Hh) { hv = ybins[tid]; scan[tid] = hv; }
    __syncthreads();
    for (int off = 1; off < Hh; off <<= 1) {
        uint32_t v2 = 0;
        if (tid < Hh) v2 = scan[tid] + ((tid >= off) ? scan[tid - off] : 0u);
        __syncthreads();
        if (tid < Hh) scan[tid] = v2;
        __syncthreads();
    }
    if (tid < Hh) ybins[tid] = scan[tid] - hv;   // exclusive base; reused as cursor
    __syncthreads();

    // scatter winners grouped by y: kp_sorted[b*KK + j] = (rank<<32)|idx
    for (uint32_t p = tid; p < m; p += 1024) {
        uint32_t rank = rnk[p];
        if (rank < KK) {
            uint32_t idx = ~((uint32_t)keys2[p]);
            uint32_t j = atomicAdd(&ybins[idx / Ww], 1u);
            kp_sorted[(size_t)b * KK + j] = ((uint64_t)rank << 32) | idx;
        }
    }
}

// 4 keypoints per 256-thread block (one per wave), in y-sorted order for DRAM locality.
__global__ __launch_bounds__(256) void gather_desc(const float* __restrict__ unet,
                                                   const uint64_t* __restrict__ kp_sorted,
                                                   float* __restrict__ out_desc) {
    int kp = blockIdx.x * 4 + (threadIdx.x >> 6);
    int lane = threadIdx.x & 63;
    int b = kp >> 11;
    uint64_t e = kp_sorted[kp];
    uint32_t idx  = (uint32_t)e;
    uint32_t rank = (uint32_t)(e >> 32);
    float v0 = 0.0f, v1 = 0.0f;
    if (idx < (uint32_t)HW) {
        const float* base = unet + (size_t)b * Cc * HW + idx;
        v0 = base[(size_t)lane * HW];
        v1 = base[(size_t)(lane + 64) * HW];
    }
    float s = v0 * v0 + v1 * v1;
    #pragma unroll
    for (int off = 32; off > 0; off >>= 1) s += __shfl_xor(s, off);
    float rn = 1.0f / fmaxf(sqrtf(s), 1e-12f);
    if (rank < KK) {
        float* o = out_desc + ((size_t)b * KK + rank) * DESC;
        o[lane]      = v0 * rn;
        o[lane + 64] = v1 * rn;
    }
}

extern "C" void kernel_launch(void* const* d_in, const int* in_sizes, int n_in,
                              void* d_out, int out_size, void* d_ws, size_t ws_size,
                              hipStream_t stream) {
    const float* unet = (const float*)d_in[0];
    float* out = (float*)d_out;
    uint8_t* ws = (uint8_t*)d_ws;

    uint64_t* cand      = (uint64_t*)ws;                                    // 1 MiB
    uint32_t* cnt       = (uint32_t*)(ws + (size_t)Bb * CAND_CAP * 8);      // 1 KiB
    uint64_t* kp_sorted = (uint64_t*)(ws + (size_t)Bb * CAND_CAP * 8 + 4096); // 64 KiB

    float* out_desc = out + (size_t)Bb * KK * 2 + (size_t)Bb * KK;

    zero_counters<<<1, Bb * NSEG, 0, stream>>>(cnt);
    nms_collect<<<NMS_BLOCKS, 256, 0, stream>>>(unet, cand, cnt);
    topk_rank<<<Bb, 1024, 0, stream>>>(cand, cnt, out, kp_sorted);
    gather_desc<<<Bb * KK / 4, 256, 0, stream>>>(unet, kp_sorted, out_desc);
}